// Round 7
// baseline (3478.748 us; speedup 1.0000x reference)
//
#include <hip/hip_runtime.h>
#include <stdint.h>
#include <stddef.h>

// Routed 2-cell LSTM, B=64, S=512, E=H=256.
// Phase 1 (xproj_kernel): precompute xg[t][g][b] = routed-cell W_ih·x_t + bias.
// Phase 2 (mlstm_rec_kernel, 32 persistent wgs): recurrence with EPOCH-IN-WORD
//   h exchange: each h value published as one 4B word {hi_bf16<<16 | epoch16}
//   (aligned 32b stores are single-copy atomic). Consumers validate epochs on
//   every word -> NO producer ack-wait, NO flags, NO flag-poll RTT. Double
//   parity buffers make overwrite-before-read impossible. h is bf16-hi only
//   (payload 64KB/wg/step); weights stay split hi/lo (2 MFMA passes).

#define BB   64
#define SS   512
#define EE   256
#define HH   256
#define G4   1024
#define NWG  32
#define TPB  512
#define TCH  32

typedef __attribute__((ext_vector_type(8))) short short8;
typedef __attribute__((ext_vector_type(4))) float f32x4;
typedef __attribute__((ext_vector_type(4))) unsigned int uint4v;

__device__ __forceinline__ unsigned short f2bf(float f){
  union { float f; unsigned u; } v; v.f = f;
  return (unsigned short)((v.u + 0x7fffu + ((v.u >> 16) & 1u)) >> 16);
}
__device__ __forceinline__ float bf2f(unsigned short s){
  union { float f; unsigned u; } v; v.u = ((unsigned)s) << 16;
  return v.f;
}

// ws layout (bytes):
// [1024, +131072)      : h words, 2 parities x 16384 uint {hi<<16|epoch}
// [132096, +134217728) : xg[t=512][g=1024][b=64] fp32 (routed-cell gates)
#define WS_H_OFF  1024
#define WS_XG_OFF (1024 + 131072)

__global__ void zero_ws_kernel(int* ws){
  const int n = (WS_H_OFF + 131072) / 4;
  for (int i = blockIdx.x * blockDim.x + threadIdx.x; i < n; i += gridDim.x * blockDim.x)
    ws[i] = 0;
}

// ---------------- Phase 1: x-projection GEMM (unchanged numerics) ----------------
__global__ __launch_bounds__(TPB, 1)
void xproj_kernel(const int* __restrict__ input, const int* __restrict__ assign,
                  const float* __restrict__ emb, const float* __restrict__ Wih,
                  const float* __restrict__ bih, const float* __restrict__ bhh,
                  float* __restrict__ xg)
{
  __shared__ __align__(16) unsigned short sXp[8][4][4][16][8];
  __shared__ int sTokP[TCH][64];
  __shared__ int sAsgP[TCH][64];

  const int tid  = threadIdx.x;
  const int lane = tid & 63;
  const int lg   = lane >> 4;
  const int lc   = lane & 15;
  const int wv   = tid >> 6;
  const int rowtile = blockIdx.x & 15;
  const int tc      = blockIdx.x >> 4;

  const int rbase = rowtile * 128 + wv * 16;
  const int cellw = rbase >> 10;
  const int rrw   = rbase & 1023;

  short8 aX[8];
  {
    const float* pw = Wih + ((size_t)cellw * G4 + (rrw + lc)) * EE + lg * 8;
    #pragma unroll
    for (int kc = 0; kc < 8; ++kc){
      const f32x4 u = *(const f32x4*)(pw + kc * 32);
      const f32x4 v = *(const f32x4*)(pw + kc * 32 + 4);
      short8 x8;
      #pragma unroll
      for (int e = 0; e < 4; ++e){ x8[e] = (short)f2bf(u[e]); x8[4+e] = (short)f2bf(v[e]); }
      aX[kc] = x8;
    }
  }
  float biasr[4];
  #pragma unroll
  for (int q = 0; q < 4; ++q){
    const int idx = cellw * G4 + rrw + lg * 4 + q;
    biasr[q] = bih[idx] + bhh[idx];
  }

  for (int i = tid; i < TCH * 64; i += TPB){
    const int tl = i >> 6, b = i & 63;
    const int tok = input[b * SS + tc * TCH + tl];
    sTokP[tl][b] = tok; sAsgP[tl][b] = assign[tok];
  }
  __syncthreads();

  const int gkc = tid >> 6, glg = (tid >> 4) & 3, glc = tid & 15;
  short8 xr[4];
  auto GATHERP = [&](int tl){
    #pragma unroll
    for (int ct = 0; ct < 4; ++ct){
      const int tok = sTokP[tl][ct * 16 + glc];
      const float* ep = emb + (size_t)tok * EE + gkc * 32 + glg * 8;
      const f32x4 u = *(const f32x4*)ep;
      const f32x4 v = *(const f32x4*)(ep + 4);
      short8 x8;
      #pragma unroll
      for (int e = 0; e < 4; ++e){ x8[e] = (short)f2bf(u[e]); x8[4+e] = (short)f2bf(v[e]); }
      xr[ct] = x8;
    }
  };
  GATHERP(0);

  for (int tl = 0; tl < TCH; ++tl){
    #pragma unroll
    for (int ct = 0; ct < 4; ++ct)
      *(short8*)&sXp[gkc][glg][ct][glc][0] = xr[ct];
    __syncthreads();
    if (tl + 1 < TCH) GATHERP(tl + 1);

    f32x4 acc[4];
    #pragma unroll
    for (int ct = 0; ct < 4; ++ct){
      acc[ct][0] = biasr[0]; acc[ct][1] = biasr[1];
      acc[ct][2] = biasr[2]; acc[ct][3] = biasr[3];
    }
    #pragma unroll
    for (int kc = 0; kc < 8; ++kc){
      #pragma unroll
      for (int ct = 0; ct < 4; ++ct){
        const short8 bx = *(const short8*)&sXp[kc][lg][ct][lc][0];
        acc[ct] = __builtin_amdgcn_mfma_f32_16x16x32_bf16(aX[kc], bx, acc[ct], 0, 0, 0);
      }
    }
    float* xgt = xg + (size_t)(tc * TCH + tl) * 65536;
    #pragma unroll
    for (int ct = 0; ct < 4; ++ct){
      const int b = ct * 16 + lc;
      if (sAsgP[tl][b] == cellw){
        #pragma unroll
        for (int q = 0; q < 4; ++q)
          xgt[(rrw + lg * 4 + q) * 64 + b] = acc[ct][q];
      }
    }
    __syncthreads();
  }
}

// ---------------- Phase 2: recurrence (epoch-in-word exchange) ----------------
__global__ __launch_bounds__(TPB, 1)
void mlstm_rec_kernel(const int* __restrict__ input, const int* __restrict__ assign,
                      const float* __restrict__ Whh, float* __restrict__ out,
                      char* __restrict__ ws)
{
  __shared__ __align__(16) unsigned int sHiW[8192];  // 32 KB: staged h-hi shorts (word-packed)
  __shared__ float sG[64][68];                       // 17.4 KB: [token][gate-row], read-conflict-free
  __shared__ float sC[64][8];
  __shared__ int sAsg[3][64];

  const int tid  = threadIdx.x;
  const int lane = tid & 63;
  const int lg   = lane >> 4;
  const int lc   = lane & 15;
  const int wv   = tid >> 6;       // 0..7
  const int rt   = wv & 3;         // cell = rt>>1, gate-pair = rt&1
  const int th   = wv >> 2;        // token half
  const int wg   = blockIdx.x;     // 0..31: owns j in [wg*8, wg*8+8)
  const int cell = rt >> 1;
  const int gp   = rt & 1;

  unsigned int* hw = (unsigned int*)(ws + WS_H_OFF);
  const float* xg = (const float*)(ws + WS_XG_OFF);

  // ---- Whh A-frags hi/lo (register-resident; weights keep full precision) ----
  short8 aHiH[8], aLoH[8];
  {
    const float* ph = Whh + ((size_t)cell * G4 + (gp * 2 + (lc >> 3)) * HH + wg * 8 + (lc & 7)) * HH + lg * 8;
    #pragma unroll
    for (int kc = 0; kc < 8; ++kc){
      const f32x4 u = *(const f32x4*)(ph + kc * 32);
      const f32x4 v = *(const f32x4*)(ph + kc * 32 + 4);
      short8 hi, lo;
      #pragma unroll
      for (int e = 0; e < 4; ++e){
        const float w0 = u[e], w1 = v[e];
        const unsigned short h0 = f2bf(w0), h1 = f2bf(w1);
        hi[e] = (short)h0;   lo[e] = (short)f2bf(w0 - bf2f(h0));
        hi[4+e] = (short)h1; lo[4+e] = (short)f2bf(w1 - bf2f(h1));
      }
      aHiH[kc] = hi; aLoH[kc] = lo;
    }
  }

  if (tid < 64){
    const int t0 = input[tid * SS];     sAsg[0][tid] = assign[t0];
    const int t1 = input[tid * SS + 1]; sAsg[1][tid] = assign[t1];
  }

  float xpre[8];
  const int xrow = (gp * 2 + (lg >> 1)) * HH + wg * 8 + (lg & 1) * 4;
  auto XPRE = [&](int t){
    const float* p = xg + (size_t)t * 65536 + xrow * 64 + th * 32 + lc;
    #pragma unroll
    for (int i = 0; i < 2; ++i)
      #pragma unroll
      for (int q = 0; q < 4; ++q)
        xpre[i * 4 + q] = p[q * 64 + i * 16];
  };
  XPRE(0);
  __syncthreads();

  const int ub = tid >> 3;     // update batch 0..63
  const int uj = tid & 7;      // update j-local 0..7

  for (int t = 0; t < SS; ++t){
    // ---- epoch-validated h acquire (no flags, no producer ack) ----
    if (t > 0){
      const unsigned int need = (unsigned int)t;
      const unsigned int* bw = hw + (size_t)(t & 1) * 16384;

      // cheap probe: one word per producer slice (32 words, 2 lines)
      int ok;
      do {
        int fl = 1;
        if (lane < NWG){
          unsigned int w;
          asm volatile("global_load_dword %0, %1, off sc0 sc1\n\ts_waitcnt vmcnt(0)"
                       : "=v"(w) : "v"(bw + lane * 512) : "memory");
          fl = ((w & 0xFFFFu) == need);
        }
        ok = (__ballot(fl == 0) == 0ull);
        if (!ok) __builtin_amdgcn_s_sleep(1);
      } while (!ok);

      // full load, validate every epoch, retry whole wave if any stale
      uint4v hv[8];
      unsigned long long badmask;
      do {
        #pragma unroll
        for (int i = 0; i < 8; ++i){
          asm volatile("global_load_dwordx4 %0, %1, off sc0 sc1"
                       : "=v"(hv[i]) : "v"(bw + tid * 32 + i * 4) : "memory");
        }
        asm volatile("s_waitcnt vmcnt(0)" ::: "memory");
        int bad = 0;
        #pragma unroll
        for (int i = 0; i < 8; ++i)
          #pragma unroll
          for (int e = 0; e < 4; ++e)
            bad |= ((hv[i][e] & 0xFFFFu) != need);
        badmask = __ballot(bad != 0);
      } while (badmask);

      // pack {hi<<16|ep},{...} pairs -> one uint of 2 bf16-hi shorts; stage to LDS
      #pragma unroll
      for (int i = 0; i < 4; ++i){
        uint4v pk;
        pk[0] = (hv[2*i][0]   >> 16) | (hv[2*i][1]   & 0xFFFF0000u);
        pk[1] = (hv[2*i][2]   >> 16) | (hv[2*i][3]   & 0xFFFF0000u);
        pk[2] = (hv[2*i+1][0] >> 16) | (hv[2*i+1][1] & 0xFFFF0000u);
        pk[3] = (hv[2*i+1][2] >> 16) | (hv[2*i+1][3] & 0xFFFF0000u);
        *(uint4v*)&sHiW[tid * 16 + i * 4] = pk;
      }
      __syncthreads();
    }

    // ---- acc init from xg; prefetch next step + routing ----
    f32x4 acc[2];
    #pragma unroll
    for (int i = 0; i < 2; ++i)
      #pragma unroll
      for (int q = 0; q < 4; ++q)
        acc[i][q] = xpre[i * 4 + q];
    if (t + 1 < SS) XPRE(t + 1);
    if (t + 2 < SS && tid < 64){
      const int tk = input[tid * SS + (t + 2)];
      sAsg[(t + 2) % 3][tid] = assign[tk];
    }

    // ---- h-part MFMAs: (Whi + Wlo)·h_hi, 32 per wave ----
    if (t > 0){
      #pragma unroll
      for (int kch = 0; kch < 8; ++kch){
        const int byte0 = (kch * 4 + lg) * 1024 + (th * 2) * 256 + lc * 16;
        const short8 hh0 = *(const short8*)((const char*)sHiW + byte0);
        const short8 hh1 = *(const short8*)((const char*)sHiW + byte0 + 256);
        acc[0] = __builtin_amdgcn_mfma_f32_16x16x32_bf16(aHiH[kch], hh0, acc[0], 0, 0, 0);
        acc[1] = __builtin_amdgcn_mfma_f32_16x16x32_bf16(aHiH[kch], hh1, acc[1], 0, 0, 0);
        acc[0] = __builtin_amdgcn_mfma_f32_16x16x32_bf16(aLoH[kch], hh0, acc[0], 0, 0, 0);
        acc[1] = __builtin_amdgcn_mfma_f32_16x16x32_bf16(aLoH[kch], hh1, acc[1], 0, 0, 0);
      }
    }

    // ---- gate exchange: sG[token][row] ----
    #pragma unroll
    for (int q = 0; q < 4; ++q){
      const int row = rt * 16 + lg * 4 + q;
      sG[(th * 2) * 16 + lc][row]     = acc[0][q];
      sG[(th * 2 + 1) * 16 + lc][row] = acc[1][q];
    }
    __syncthreads();

    // ---- pointwise update, publish {hi|epoch} word (fire-and-forget) ----
    {
      const int a = sAsg[t % 3][ub];
      const int r0 = a * 32 + uj;
      const float gi = sG[ub][r0];
      const float gf = sG[ub][r0 + 8];
      const float gg = sG[ub][r0 + 16];
      const float go = sG[ub][r0 + 24];
      const float cold = (t == 0) ? 0.f : sC[ub][uj];
      const float si = 1.f / (1.f + __expf(-gi));
      const float sf = 1.f / (1.f + __expf(-gf));
      const float so = 1.f / (1.f + __expf(-go));
      const float cn = sf * cold + si * tanhf(gg);
      const float hn = so * tanhf(cn);
      const int j = wg * 8 + uj;
      if (t < SS - 1){
        sC[ub][uj] = cn;
        const unsigned int word = ((unsigned int)f2bf(hn) << 16) | ((unsigned int)(t + 1) & 0xFFFFu);
        unsigned int* dst = hw + (size_t)((t & 1) ^ 1) * 16384
                          + wg * 512 + (ub >> 4) * 128 + (ub & 15) * 8 + uj;
        asm volatile("global_store_dword %0, %1, off sc0 sc1" :: "v"(dst), "v"(word) : "memory");
      } else {
        out[ub * 512 + j]       = hn;
        out[ub * 512 + 256 + j] = cn;
      }
    }
    // no release machinery: the epoch inside each word IS the flag.
  }
}

extern "C" void kernel_launch(void* const* d_in, const int* in_sizes, int n_in,
                              void* d_out, int out_size, void* d_ws, size_t ws_size,
                              hipStream_t stream)
{
  const int*   input  = (const int*)  d_in[0];
  const int*   assign = (const int*)  d_in[1];
  const float* emb    = (const float*)d_in[2];
  const float* Wih    = (const float*)d_in[3];
  const float* Whh    = (const float*)d_in[4];
  const float* bih    = (const float*)d_in[5];
  const float* bhh    = (const float*)d_in[6];
  float* out = (float*)d_out;
  char*  ws  = (char*)d_ws;

  zero_ws_kernel<<<64, 256, 0, stream>>>((int*)ws);
  float* xg = (float*)(ws + WS_XG_OFF);
  xproj_kernel<<<256, TPB, 0, stream>>>(input, assign, emb, Wih, bih, bhh, xg);
  mlstm_rec_kernel<<<NWG, TPB, 0, stream>>>(input, assign, Whh, out, ws);
}

// Round 8
// 2076.871 us; speedup vs baseline: 1.6750x; 1.6750x over previous
//
#include <hip/hip_runtime.h>
#include <stdint.h>
#include <stddef.h>

// Routed 2-cell LSTM, B=64, S=512, E=H=256.
// Phase 1 (xproj_kernel): precompute xg[t][g][b] = routed-cell W_ih·x_t + bias.
// Phase 2 (mlstm_rec_kernel, 32 persistent wgs): recurrence; h exchanged as
//   bf16-HI ONLY (32 KB/step, validated by round 7: absmax unchanged) via
//   IF-coherent (sc0 sc1) dword stores; round-6 flag release/acquire protocol
//   (proven): h stores ack'd at IF -> per-wg flag store -> consumers poll 32
//   flags in parallel. Weights stay split hi/lo (32 MFMAs/wave).

#define BB   64
#define SS   512
#define EE   256
#define HH   256
#define G4   1024
#define NWG  32
#define TPB  512
#define TCH  32

typedef __attribute__((ext_vector_type(8))) short short8;
typedef __attribute__((ext_vector_type(4))) float f32x4;

__device__ __forceinline__ unsigned short f2bf(float f){
  union { float f; unsigned u; } v; v.f = f;
  return (unsigned short)((v.u + 0x7fffu + ((v.u >> 16) & 1u)) >> 16);
}
__device__ __forceinline__ float bf2f(unsigned short s){
  union { float f; unsigned u; } v; v.u = ((unsigned)s) << 16;
  return v.f;
}
__device__ __forceinline__ int swz(int byte){ return byte ^ (((byte >> 10) & 3) << 6); }

// ws layout (bytes):
// [0,128)              : flags[32]
// [1024, +65536)       : h-hi shorts, 2 parities x 32KB
// [132096, +134217728) : xg[t=512][g=1024][b=64] fp32 (routed-cell gates)
#define WS_H_OFF  1024
#define WS_XG_OFF (1024 + 131072)

__global__ void zero_flags_kernel(int* ws){
  if (threadIdx.x < 256) ws[threadIdx.x] = 0;
}

// ---------------- Phase 1: x-projection GEMM ----------------
__global__ __launch_bounds__(TPB, 1)
void xproj_kernel(const int* __restrict__ input, const int* __restrict__ assign,
                  const float* __restrict__ emb, const float* __restrict__ Wih,
                  const float* __restrict__ bih, const float* __restrict__ bhh,
                  float* __restrict__ xg)
{
  __shared__ __align__(16) unsigned short sXp[8][4][4][16][8];
  __shared__ int sTokP[TCH][64];
  __shared__ int sAsgP[TCH][64];

  const int tid  = threadIdx.x;
  const int lane = tid & 63;
  const int lg   = lane >> 4;
  const int lc   = lane & 15;
  const int wv   = tid >> 6;
  const int rowtile = blockIdx.x & 15;
  const int tc      = blockIdx.x >> 4;

  const int rbase = rowtile * 128 + wv * 16;
  const int cellw = rbase >> 10;
  const int rrw   = rbase & 1023;

  short8 aX[8];
  {
    const float* pw = Wih + ((size_t)cellw * G4 + (rrw + lc)) * EE + lg * 8;
    #pragma unroll
    for (int kc = 0; kc < 8; ++kc){
      const f32x4 u = *(const f32x4*)(pw + kc * 32);
      const f32x4 v = *(const f32x4*)(pw + kc * 32 + 4);
      short8 x8;
      #pragma unroll
      for (int e = 0; e < 4; ++e){ x8[e] = (short)f2bf(u[e]); x8[4+e] = (short)f2bf(v[e]); }
      aX[kc] = x8;
    }
  }
  float biasr[4];
  #pragma unroll
  for (int q = 0; q < 4; ++q){
    const int idx = cellw * G4 + rrw + lg * 4 + q;
    biasr[q] = bih[idx] + bhh[idx];
  }

  for (int i = tid; i < TCH * 64; i += TPB){
    const int tl = i >> 6, b = i & 63;
    const int tok = input[b * SS + tc * TCH + tl];
    sTokP[tl][b] = tok; sAsgP[tl][b] = assign[tok];
  }
  __syncthreads();

  const int gkc = tid >> 6, glg = (tid >> 4) & 3, glc = tid & 15;
  short8 xr[4];
  auto GATHERP = [&](int tl){
    #pragma unroll
    for (int ct = 0; ct < 4; ++ct){
      const int tok = sTokP[tl][ct * 16 + glc];
      const float* ep = emb + (size_t)tok * EE + gkc * 32 + glg * 8;
      const f32x4 u = *(const f32x4*)ep;
      const f32x4 v = *(const f32x4*)(ep + 4);
      short8 x8;
      #pragma unroll
      for (int e = 0; e < 4; ++e){ x8[e] = (short)f2bf(u[e]); x8[4+e] = (short)f2bf(v[e]); }
      xr[ct] = x8;
    }
  };
  GATHERP(0);

  for (int tl = 0; tl < TCH; ++tl){
    #pragma unroll
    for (int ct = 0; ct < 4; ++ct)
      *(short8*)&sXp[gkc][glg][ct][glc][0] = xr[ct];
    __syncthreads();
    if (tl + 1 < TCH) GATHERP(tl + 1);

    f32x4 acc[4];
    #pragma unroll
    for (int ct = 0; ct < 4; ++ct){
      acc[ct][0] = biasr[0]; acc[ct][1] = biasr[1];
      acc[ct][2] = biasr[2]; acc[ct][3] = biasr[3];
    }
    #pragma unroll
    for (int kc = 0; kc < 8; ++kc){
      #pragma unroll
      for (int ct = 0; ct < 4; ++ct){
        const short8 bx = *(const short8*)&sXp[kc][lg][ct][lc][0];
        acc[ct] = __builtin_amdgcn_mfma_f32_16x16x32_bf16(aX[kc], bx, acc[ct], 0, 0, 0);
      }
    }
    float* xgt = xg + (size_t)(tc * TCH + tl) * 65536;
    #pragma unroll
    for (int ct = 0; ct < 4; ++ct){
      const int b = ct * 16 + lc;
      if (sAsgP[tl][b] == cellw){
        #pragma unroll
        for (int q = 0; q < 4; ++q)
          xgt[(rrw + lg * 4 + q) * 64 + b] = acc[ct][q];
      }
    }
    __syncthreads();
  }
}

// ---------------- Phase 2: recurrence (32 wgs, flags + hi-only h) ----------------
__global__ __launch_bounds__(TPB, 1)
void mlstm_rec_kernel(const int* __restrict__ input, const int* __restrict__ assign,
                      const float* __restrict__ Whh, float* __restrict__ out,
                      char* __restrict__ ws)
{
  __shared__ __align__(16) unsigned short sH[16384];  // 32 KB staged h-hi, swizzled
  __shared__ float sG[64][68];                        // [token][gate-row]
  __shared__ float sC[64][8];
  __shared__ int sAsg[3][64];

  const int tid  = threadIdx.x;
  const int lane = tid & 63;
  const int lg   = lane >> 4;
  const int lc   = lane & 15;
  const int wv   = tid >> 6;       // 0..7
  const int rt   = wv & 3;         // cell = rt>>1, gate-pair = rt&1
  const int th   = wv >> 2;        // token half
  const int wg   = blockIdx.x;     // 0..31: owns j in [wg*8, wg*8+8)
  const int cell = rt >> 1;
  const int gp   = rt & 1;

  int* flags = (int*)ws;
  unsigned short* hbuf = (unsigned short*)(ws + WS_H_OFF);
  const float* xg = (const float*)(ws + WS_XG_OFF);

  // ---- Whh A-frags hi/lo (register-resident; weights full precision) ----
  short8 aHiH[8], aLoH[8];
  {
    const float* ph = Whh + ((size_t)cell * G4 + (gp * 2 + (lc >> 3)) * HH + wg * 8 + (lc & 7)) * HH + lg * 8;
    #pragma unroll
    for (int kc = 0; kc < 8; ++kc){
      const f32x4 u = *(const f32x4*)(ph + kc * 32);
      const f32x4 v = *(const f32x4*)(ph + kc * 32 + 4);
      short8 hi, lo;
      #pragma unroll
      for (int e = 0; e < 4; ++e){
        const float w0 = u[e], w1 = v[e];
        const unsigned short h0 = f2bf(w0), h1 = f2bf(w1);
        hi[e] = (short)h0;   lo[e] = (short)f2bf(w0 - bf2f(h0));
        hi[4+e] = (short)h1; lo[4+e] = (short)f2bf(w1 - bf2f(h1));
      }
      aHiH[kc] = hi; aLoH[kc] = lo;
    }
  }

  if (tid < 64){
    const int t0 = input[tid * SS];     sAsg[0][tid] = assign[t0];
    const int t1 = input[tid * SS + 1]; sAsg[1][tid] = assign[t1];
  }

  float xpre[8];
  const int xrow = (gp * 2 + (lg >> 1)) * HH + wg * 8 + (lg & 1) * 4;
  auto XPRE = [&](int t){
    const float* p = xg + (size_t)t * 65536 + xrow * 64 + th * 32 + lc;
    #pragma unroll
    for (int i = 0; i < 2; ++i)
      #pragma unroll
      for (int q = 0; q < 4; ++q)
        xpre[i * 4 + q] = p[q * 64 + i * 16];
  };
  XPRE(0);
  __syncthreads();

  const int ub  = tid >> 2;        // update batch 0..63 (tid<256)
  const int ujp = (tid & 3) * 2;   // update j-local pair base: 0,2,4,6

  for (int t = 0; t < SS; ++t){
    // ---- wait for all 32 flags >= t (parallel poll, sc0 sc1) ----
    if (t > 0){
      const int need = t;
      const int* fp2 = &flags[lane & 31];
      int fl = need;
      do {
        if (lane < NWG){
          int tmp;
          asm volatile("global_load_dword %0, %1, off sc0 sc1\n\ts_waitcnt vmcnt(0)"
                       : "=v"(tmp) : "v"(fp2) : "memory");
          fl = tmp;
          if (tmp < need) __builtin_amdgcn_s_sleep(1);
        }
      } while (__ballot(fl < need));

      // ---- load + stage h-hi (32 KB, 4 x dwordx4 per thread) ----
      const unsigned short* hr = hbuf + (size_t)(t & 1) * 16384;
      short8 hcp[4];
      #pragma unroll
      for (int i = 0; i < 4; ++i){
        const unsigned short* p = hr + (i * 512 + tid) * 8;
        asm volatile("global_load_dwordx4 %0, %1, off sc0 sc1"
                     : "=v"(hcp[i]) : "v"(p) : "memory");
      }
      asm volatile("s_waitcnt vmcnt(0)" ::: "memory");
      __builtin_amdgcn_sched_barrier(0);
      #pragma unroll
      for (int i = 0; i < 4; ++i)
        *(short8*)((char*)sH + swz((i * 512 + tid) * 16)) = hcp[i];
      __syncthreads();
    }

    // ---- acc init from xg; prefetch next step + routing ----
    f32x4 acc[2];
    #pragma unroll
    for (int i = 0; i < 2; ++i)
      #pragma unroll
      for (int q = 0; q < 4; ++q)
        acc[i][q] = xpre[i * 4 + q];
    if (t + 1 < SS) XPRE(t + 1);
    if (t + 2 < SS && tid < 64){
      const int tk = input[tid * SS + (t + 2)];
      sAsg[(t + 2) % 3][tid] = assign[tk];
    }

    // ---- h-part MFMAs: (Whi + Wlo)·h_hi, 32 per wave ----
    if (t > 0){
      #pragma unroll
      for (int kch = 0; kch < 8; ++kch){
        const int base = (kch * 4 + lg) * 1024 + th * 512 + lc * 16;
        const short8 hh0 = *(const short8*)((const char*)sH + swz(base));
        const short8 hh1 = *(const short8*)((const char*)sH + swz(base + 256));
        acc[0] = __builtin_amdgcn_mfma_f32_16x16x32_bf16(aHiH[kch], hh0, acc[0], 0, 0, 0);
        acc[1] = __builtin_amdgcn_mfma_f32_16x16x32_bf16(aHiH[kch], hh1, acc[1], 0, 0, 0);
        acc[0] = __builtin_amdgcn_mfma_f32_16x16x32_bf16(aLoH[kch], hh0, acc[0], 0, 0, 0);
        acc[1] = __builtin_amdgcn_mfma_f32_16x16x32_bf16(aLoH[kch], hh1, acc[1], 0, 0, 0);
      }
    }

    // ---- gate exchange: sG[token][row] ----
    #pragma unroll
    for (int q = 0; q < 4; ++q){
      const int row = rt * 16 + lg * 4 + q;
      sG[(th * 2) * 16 + lc][row]     = acc[0][q];
      sG[(th * 2 + 1) * 16 + lc][row] = acc[1][q];
    }
    __syncthreads();

    // ---- pointwise update (tid<256: one (b, j-pair)), publish h as dword ----
    if (tid < 256){
      const int a = sAsg[t % 3][ub];
      const int r0 = a * 32 + ujp;
      const float gi0 = sG[ub][r0],      gi1 = sG[ub][r0 + 1];
      const float gf0 = sG[ub][r0 + 8],  gf1 = sG[ub][r0 + 9];
      const float gg0 = sG[ub][r0 + 16], gg1 = sG[ub][r0 + 17];
      const float go0 = sG[ub][r0 + 24], go1 = sG[ub][r0 + 25];
      const float c0 = (t == 0) ? 0.f : sC[ub][ujp];
      const float c1 = (t == 0) ? 0.f : sC[ub][ujp + 1];
      const float si0 = 1.f / (1.f + __expf(-gi0)), si1 = 1.f / (1.f + __expf(-gi1));
      const float sf0 = 1.f / (1.f + __expf(-gf0)), sf1 = 1.f / (1.f + __expf(-gf1));
      const float so0 = 1.f / (1.f + __expf(-go0)), so1 = 1.f / (1.f + __expf(-go1));
      const float cn0 = sf0 * c0 + si0 * tanhf(gg0);
      const float cn1 = sf1 * c1 + si1 * tanhf(gg1);
      const float hn0 = so0 * tanhf(cn0);
      const float hn1 = so1 * tanhf(cn1);
      const int j = wg * 8 + ujp;
      if (t < SS - 1){
        sC[ub][ujp] = cn0; sC[ub][ujp + 1] = cn1;
        const unsigned word = (unsigned)f2bf(hn0) | ((unsigned)f2bf(hn1) << 16);
        // dword index: (j>>3)*256 + (b>>4)*64 + (b&15)*4 + (jl>>1)
        unsigned int* hw = (unsigned int*)(hbuf + (size_t)((t & 1) ^ 1) * 16384);
        unsigned int* dst = hw + wg * 256 + (ub >> 4) * 64 + (ub & 15) * 4 + (ujp >> 1);
        asm volatile("global_store_dword %0, %1, off sc0 sc1" :: "v"(dst), "v"(word) : "memory");
      } else {
        out[ub * 512 + j]           = hn0;
        out[ub * 512 + j + 1]       = hn1;
        out[ub * 512 + 256 + j]     = cn0;
        out[ub * 512 + 256 + j + 1] = cn1;
      }
    }

    // ---- release: h stores ack'd at IF, then set own flag (no RMW) ----
    if (t < SS - 1){
      asm volatile("s_waitcnt vmcnt(0)" ::: "memory");
      __syncthreads();
      if (tid == 0){
        const int val = t + 1;
        int* fp = &flags[wg];
        asm volatile("global_store_dword %0, %1, off sc0 sc1" :: "v"(fp), "v"(val) : "memory");
      }
    }
  }
}

extern "C" void kernel_launch(void* const* d_in, const int* in_sizes, int n_in,
                              void* d_out, int out_size, void* d_ws, size_t ws_size,
                              hipStream_t stream)
{
  const int*   input  = (const int*)  d_in[0];
  const int*   assign = (const int*)  d_in[1];
  const float* emb    = (const float*)d_in[2];
  const float* Wih    = (const float*)d_in[3];
  const float* Whh    = (const float*)d_in[4];
  const float* bih    = (const float*)d_in[5];
  const float* bhh    = (const float*)d_in[6];
  float* out = (float*)d_out;
  char*  ws  = (char*)d_ws;

  zero_flags_kernel<<<1, 256, 0, stream>>>((int*)ws);
  float* xg = (float*)(ws + WS_XG_OFF);
  xproj_kernel<<<256, TPB, 0, stream>>>(input, assign, emb, Wih, bih, bhh, xg);
  mlstm_rec_kernel<<<NWG, TPB, 0, stream>>>(input, assign, Whh, out, ws);
}

// Round 9
// 2042.157 us; speedup vs baseline: 1.7035x; 1.0170x over previous
//
#include <hip/hip_runtime.h>
#include <stdint.h>
#include <stddef.h>

// Routed 2-cell LSTM, B=64, S=512, E=H=256.
// Phase 1 (xproj_kernel): precompute xg[t][g][b] = routed-cell W_ih·x_t + bias.
// Phase 2 (mlstm_rec_kernel, 32 persistent wgs): recurrence with UPDATE-READY
//   MFMA row ordering: wave's 16 weight rows ordered m=(j_sub<<2)|gate, so
//   each lane's acc[q] = {i,f,g,o} for one (j,token) -> in-register pointwise
//   update, NO gate-exchange LDS phase. h published hi-bf16 via 1KB LDS
//   bounce -> one wave's 64 coalesced dwordx4 sc0/sc1 stores -> flag.
//   Only wave 0 polls flags (8x less IF hot-line traffic).

#define BB   64
#define SS   512
#define EE   256
#define HH   256
#define G4   1024
#define NWG  32
#define TPB  512
#define TCH  32

typedef __attribute__((ext_vector_type(8))) short short8;
typedef __attribute__((ext_vector_type(4))) float f32x4;

__device__ __forceinline__ unsigned short f2bf(float f){
  union { float f; unsigned u; } v; v.f = f;
  return (unsigned short)((v.u + 0x7fffu + ((v.u >> 16) & 1u)) >> 16);
}
__device__ __forceinline__ float bf2f(unsigned short s){
  union { float f; unsigned u; } v; v.u = ((unsigned)s) << 16;
  return v.f;
}
__device__ __forceinline__ int swz(int byte){ return byte ^ (((byte >> 10) & 3) << 6); }

// ws layout (bytes):
// [0,128)              : flags[32]
// [1024, +65536)       : h-hi shorts, 2 parities x 32KB
// [132096, +134217728) : xg[t=512][g=1024][b=64] fp32 (routed-cell gates)
#define WS_H_OFF  1024
#define WS_XG_OFF (1024 + 131072)

__global__ void zero_flags_kernel(int* ws){
  if (threadIdx.x < 256) ws[threadIdx.x] = 0;
}

// ---------------- Phase 1: x-projection GEMM ----------------
__global__ __launch_bounds__(TPB, 1)
void xproj_kernel(const int* __restrict__ input, const int* __restrict__ assign,
                  const float* __restrict__ emb, const float* __restrict__ Wih,
                  const float* __restrict__ bih, const float* __restrict__ bhh,
                  float* __restrict__ xg)
{
  __shared__ __align__(16) unsigned short sXp[8][4][4][16][8];
  __shared__ int sTokP[TCH][64];
  __shared__ int sAsgP[TCH][64];

  const int tid  = threadIdx.x;
  const int lane = tid & 63;
  const int lg   = lane >> 4;
  const int lc   = lane & 15;
  const int wv   = tid >> 6;
  const int rowtile = blockIdx.x & 15;
  const int tc      = blockIdx.x >> 4;

  const int rbase = rowtile * 128 + wv * 16;
  const int cellw = rbase >> 10;
  const int rrw   = rbase & 1023;

  short8 aX[8];
  {
    const float* pw = Wih + ((size_t)cellw * G4 + (rrw + lc)) * EE + lg * 8;
    #pragma unroll
    for (int kc = 0; kc < 8; ++kc){
      const f32x4 u = *(const f32x4*)(pw + kc * 32);
      const f32x4 v = *(const f32x4*)(pw + kc * 32 + 4);
      short8 x8;
      #pragma unroll
      for (int e = 0; e < 4; ++e){ x8[e] = (short)f2bf(u[e]); x8[4+e] = (short)f2bf(v[e]); }
      aX[kc] = x8;
    }
  }
  float biasr[4];
  #pragma unroll
  for (int q = 0; q < 4; ++q){
    const int idx = cellw * G4 + rrw + lg * 4 + q;
    biasr[q] = bih[idx] + bhh[idx];
  }

  for (int i = tid; i < TCH * 64; i += TPB){
    const int tl = i >> 6, b = i & 63;
    const int tok = input[b * SS + tc * TCH + tl];
    sTokP[tl][b] = tok; sAsgP[tl][b] = assign[tok];
  }
  __syncthreads();

  const int gkc = tid >> 6, glg = (tid >> 4) & 3, glc = tid & 15;
  short8 xr[4];
  auto GATHERP = [&](int tl){
    #pragma unroll
    for (int ct = 0; ct < 4; ++ct){
      const int tok = sTokP[tl][ct * 16 + glc];
      const float* ep = emb + (size_t)tok * EE + gkc * 32 + glg * 8;
      const f32x4 u = *(const f32x4*)ep;
      const f32x4 v = *(const f32x4*)(ep + 4);
      short8 x8;
      #pragma unroll
      for (int e = 0; e < 4; ++e){ x8[e] = (short)f2bf(u[e]); x8[4+e] = (short)f2bf(v[e]); }
      xr[ct] = x8;
    }
  };
  GATHERP(0);

  for (int tl = 0; tl < TCH; ++tl){
    #pragma unroll
    for (int ct = 0; ct < 4; ++ct)
      *(short8*)&sXp[gkc][glg][ct][glc][0] = xr[ct];
    __syncthreads();
    if (tl + 1 < TCH) GATHERP(tl + 1);

    f32x4 acc[4];
    #pragma unroll
    for (int ct = 0; ct < 4; ++ct){
      acc[ct][0] = biasr[0]; acc[ct][1] = biasr[1];
      acc[ct][2] = biasr[2]; acc[ct][3] = biasr[3];
    }
    #pragma unroll
    for (int kc = 0; kc < 8; ++kc){
      #pragma unroll
      for (int ct = 0; ct < 4; ++ct){
        const short8 bx = *(const short8*)&sXp[kc][lg][ct][lc][0];
        acc[ct] = __builtin_amdgcn_mfma_f32_16x16x32_bf16(aX[kc], bx, acc[ct], 0, 0, 0);
      }
    }
    float* xgt = xg + (size_t)(tc * TCH + tl) * 65536;
    #pragma unroll
    for (int ct = 0; ct < 4; ++ct){
      const int b = ct * 16 + lc;
      if (sAsgP[tl][b] == cellw){
        #pragma unroll
        for (int q = 0; q < 4; ++q)
          xgt[(rrw + lg * 4 + q) * 64 + b] = acc[ct][q];
      }
    }
    __syncthreads();
  }
}

// ---------------- Phase 2: recurrence (update-ready acc layout) ----------------
__global__ __launch_bounds__(TPB, 1)
void mlstm_rec_kernel(const int* __restrict__ input, const int* __restrict__ assign,
                      const float* __restrict__ Whh, float* __restrict__ out,
                      char* __restrict__ ws)
{
  __shared__ __align__(16) unsigned short sH[16384];   // 32 KB staged h-hi, swizzled
  __shared__ unsigned short sHout[64][8];              // 1 KB publish bounce
  __shared__ float sC[64][8];                          // 2 KB c-state
  __shared__ int sAsg[3][64];

  const int tid  = threadIdx.x;
  const int lane = tid & 63;
  const int lg   = lane >> 4;
  const int lc   = lane & 15;
  const int wv   = tid >> 6;        // 0..7
  const int cell  = wv & 1;
  const int jhalf = (wv >> 1) & 1;
  const int th    = wv >> 2;        // token half
  const int wg    = blockIdx.x;     // owns j in [wg*8, wg*8+8)

  int* flags = (int*)ws;
  unsigned short* hbuf = (unsigned short*)(ws + WS_H_OFF);
  const float* xg = (const float*)(ws + WS_XG_OFF);

  // ---- Whh A-frags hi/lo, rows ordered m=(j_sub<<2)|gate (update-ready) ----
  short8 aHiH[8], aLoH[8];
  {
    const float* ph = Whh + ((size_t)cell * G4 + (lc & 3) * HH
                             + wg * 8 + jhalf * 4 + (lc >> 2)) * HH + lg * 8;
    #pragma unroll
    for (int kc = 0; kc < 8; ++kc){
      const f32x4 u = *(const f32x4*)(ph + kc * 32);
      const f32x4 v = *(const f32x4*)(ph + kc * 32 + 4);
      short8 hi, lo;
      #pragma unroll
      for (int e = 0; e < 4; ++e){
        const float w0 = u[e], w1 = v[e];
        const unsigned short h0 = f2bf(w0), h1 = f2bf(w1);
        hi[e] = (short)h0;   lo[e] = (short)f2bf(w0 - bf2f(h0));
        hi[4+e] = (short)h1; lo[4+e] = (short)f2bf(w1 - bf2f(h1));
      }
      aHiH[kc] = hi; aLoH[kc] = lo;
    }
  }

  if (tid < 64){
    const int t0 = input[tid * SS];     sAsg[0][tid] = assign[t0];
    const int t1 = input[tid * SS + 1]; sAsg[1][tid] = assign[t1];
  }

  const int jloc  = jhalf * 4 + lg;        // 0..7
  const int jglob = wg * 8 + jloc;

  // xg prefetch: acc[ct][q] = xg[t][q*256 + jglob][th*32 + ct*16 + lc]
  float xpre[8];
  auto XPRE = [&](int t){
    const float* p = xg + (size_t)t * 65536 + jglob * 64 + th * 32 + lc;
    #pragma unroll
    for (int ct = 0; ct < 2; ++ct)
      #pragma unroll
      for (int q = 0; q < 4; ++q)
        xpre[ct * 4 + q] = p[q * 16384 + ct * 16];
  };
  XPRE(0);
  __syncthreads();

  for (int t = 0; t < SS; ++t){
    // ---- wave 0 polls flags; others wait at barrier ----
    if (t > 0){
      if (wv == 0){
        const int need = t;
        const int* fp2 = &flags[lane & 31];
        int fl = need;
        do {
          if (lane < NWG){
            int tmp;
            asm volatile("global_load_dword %0, %1, off sc0 sc1\n\ts_waitcnt vmcnt(0)"
                         : "=v"(tmp) : "v"(fp2) : "memory");
            fl = tmp;
            if (tmp < need) __builtin_amdgcn_s_sleep(1);
          }
        } while (__ballot(fl < need));
      }
      __syncthreads();

      // ---- all threads load + stage h-hi (32 KB) ----
      const unsigned short* hr = hbuf + (size_t)(t & 1) * 16384;
      short8 hcp[4];
      #pragma unroll
      for (int i = 0; i < 4; ++i){
        const unsigned short* p = hr + (i * 512 + tid) * 8;
        asm volatile("global_load_dwordx4 %0, %1, off sc0 sc1"
                     : "=v"(hcp[i]) : "v"(p) : "memory");
      }
      asm volatile("s_waitcnt vmcnt(0)" ::: "memory");
      __builtin_amdgcn_sched_barrier(0);
      #pragma unroll
      for (int i = 0; i < 4; ++i)
        *(short8*)((char*)sH + swz((i * 512 + tid) * 16)) = hcp[i];
      __syncthreads();
    }

    // ---- acc init from xg; prefetch next step + routing ----
    f32x4 acc[2];
    #pragma unroll
    for (int ct = 0; ct < 2; ++ct)
      #pragma unroll
      for (int q = 0; q < 4; ++q)
        acc[ct][q] = xpre[ct * 4 + q];
    if (t + 1 < SS) XPRE(t + 1);
    if (t + 2 < SS && tid < 64){
      const int tk = input[tid * SS + (t + 2)];
      sAsg[(t + 2) % 3][tid] = assign[tk];
    }

    // ---- h-part MFMAs: (Whi + Wlo)·h_hi, 32 per wave ----
    if (t > 0){
      #pragma unroll
      for (int kch = 0; kch < 8; ++kch){
        const int base = (kch * 4 + lg) * 1024 + th * 512 + lc * 16;
        const short8 hh0 = *(const short8*)((const char*)sH + swz(base));
        const short8 hh1 = *(const short8*)((const char*)sH + swz(base + 256));
        acc[0] = __builtin_amdgcn_mfma_f32_16x16x32_bf16(aHiH[kch], hh0, acc[0], 0, 0, 0);
        acc[1] = __builtin_amdgcn_mfma_f32_16x16x32_bf16(aHiH[kch], hh1, acc[1], 0, 0, 0);
        acc[0] = __builtin_amdgcn_mfma_f32_16x16x32_bf16(aLoH[kch], hh0, acc[0], 0, 0, 0);
        acc[1] = __builtin_amdgcn_mfma_f32_16x16x32_bf16(aLoH[kch], hh1, acc[1], 0, 0, 0);
      }
    }

    // ---- in-register pointwise update: lane has {i,f,g,o} for (jglob, token) ----
    #pragma unroll
    for (int ct = 0; ct < 2; ++ct){
      const int b = th * 32 + ct * 16 + lc;
      const int a = sAsg[t % 3][b];
      if (a == cell){
        const float gi = acc[ct][0], gf = acc[ct][1];
        const float gg = acc[ct][2], go = acc[ct][3];
        const float cold = (t == 0) ? 0.f : sC[b][jloc];
        const float si = 1.f / (1.f + __expf(-gi));
        const float sf = 1.f / (1.f + __expf(-gf));
        const float so = 1.f / (1.f + __expf(-go));
        const float cn = sf * cold + si * tanhf(gg);
        const float hn = so * tanhf(cn);
        if (t < SS - 1){
          sC[b][jloc] = cn;
          sHout[b][jloc] = f2bf(hn);
        } else {
          out[b * 512 + jglob]       = hn;
          out[b * 512 + 256 + jglob] = cn;
        }
      }
    }

    // ---- publish: one wave copy-outs 1KB coalesced, acks, flags ----
    if (t < SS - 1){
      __syncthreads();
      if (tid < 64){
        const short8 v = *(const short8*)&sHout[tid][0];
        unsigned short* dst = hbuf + (size_t)((t & 1) ^ 1) * 16384 + wg * 512 + tid * 8;
        asm volatile("global_store_dwordx4 %0, %1, off sc0 sc1" :: "v"(dst), "v"(v) : "memory");
        asm volatile("s_waitcnt vmcnt(0)" ::: "memory");
        if (tid == 0){
          const int val = t + 1;
          int* fp = &flags[wg];
          asm volatile("global_store_dword %0, %1, off sc0 sc1" :: "v"(fp), "v"(val) : "memory");
        }
      }
    }
  }
}

extern "C" void kernel_launch(void* const* d_in, const int* in_sizes, int n_in,
                              void* d_out, int out_size, void* d_ws, size_t ws_size,
                              hipStream_t stream)
{
  const int*   input  = (const int*)  d_in[0];
  const int*   assign = (const int*)  d_in[1];
  const float* emb    = (const float*)d_in[2];
  const float* Wih    = (const float*)d_in[3];
  const float* Whh    = (const float*)d_in[4];
  const float* bih    = (const float*)d_in[5];
  const float* bhh    = (const float*)d_in[6];
  float* out = (float*)d_out;
  char*  ws  = (char*)d_ws;

  zero_flags_kernel<<<1, 256, 0, stream>>>((int*)ws);
  float* xg = (float*)(ws + WS_XG_OFF);
  xproj_kernel<<<256, TPB, 0, stream>>>(input, assign, emb, Wih, bih, bhh, xg);
  mlstm_rec_kernel<<<NWG, TPB, 0, stream>>>(input, assign, Whh, out, ws);
}